// Round 1
// 628.366 us; speedup vs baseline: 1.1290x; 1.1290x over previous
//
#include <hip/hip_runtime.h>
#include <math.h>

#define NV 50000
#define NM 150000   // 50000*3 rows

// par[j] for j in 0..23 (par[0] unused); depth[j] = chain depth
__constant__ int c_par[24]   = {0, 0,0,0, 1,2,3, 4,5,6, 7,8,9,9,9, 12,13,14, 16,17, 18,19, 20,21};
__constant__ int c_depth[24] = {0, 1,1,1, 2,2,2, 3,3,3, 4,4,4,4,4, 5,5,5, 6,6, 7,7, 8,8};

// transpose beta [64][300] -> betaT [300][64]; zero J [64][24][3]
__global__ __launch_bounds__(256)
void prep_kernel(const float* __restrict__ beta, float* __restrict__ betaT,
                 float* __restrict__ J)
{
    int i = blockIdx.x * 256 + threadIdx.x;
    if (i < 300 * 64) {
        int k = i >> 6, b = i & 63;
        betaT[i] = beta[b * 300 + k];
    }
    if (i < 64 * 24 * 3) J[i] = 0.f;
}

// Batch-in-registers GEMM: C[row][b] = A[row][:K] . Bt[:K][b]
// thread = one row, half the batch (acc[32]); B values are wave-uniform -> s_load.
// MODE0: C[row*64+b] = acc + add[row]            (v_shaped,  [NM][64])
// MODE1: C[b*NM+row] = acc + add[row*64+b]       (v_posed,   [64][NM])
template<int K, int MODE>
__global__ __launch_bounds__(128)
void gemm_kernel(const float* __restrict__ A, const float* __restrict__ Bt,
                 const float* __restrict__ add, float* __restrict__ C)
{
    __shared__ float As[64 * 33];          // 64 rows x 32 k, pitch 33 (conflict-free)
    const int t    = threadIdx.x;
    const int row0 = blockIdx.x * 64;
    const int lrow = t & 63;
    const int half = __builtin_amdgcn_readfirstlane(t >> 6);   // wave-uniform 0/1
    const int row  = row0 + lrow;

    float acc[32];
    #pragma unroll
    for (int b = 0; b < 32; ++b) acc[b] = 0.f;

    const int srow = t >> 3;   // 0..15 (staging row within pass)
    const int skg  = t & 7;    // 0..7  (k-group: float4)

    const int nfull = K / 32;
    for (int c = 0; c < nfull; ++c) {
        const int k0 = c * 32;
        __syncthreads();
        // coalesced staging: 8 lanes x 16B = 128B contiguous per row
        #pragma unroll
        for (int p = 0; p < 4; ++p) {
            int r = p * 16 + srow;
            float4 v = make_float4(0.f, 0.f, 0.f, 0.f);
            if (row0 + r < NM)
                v = *(const float4*)(A + (size_t)(row0 + r) * K + k0 + skg * 4);
            float* d = As + r * 33 + skg * 4;
            d[0] = v.x; d[1] = v.y; d[2] = v.z; d[3] = v.w;
        }
        __syncthreads();
        #pragma unroll 4
        for (int k = 0; k < 32; ++k) {
            float a = As[lrow * 33 + k];
            const float* Bk = Bt + (size_t)(k0 + k) * 64 + half * 32;  // uniform -> SGPR
            #pragma unroll
            for (int b = 0; b < 32; ++b) acc[b] = fmaf(Bk[b], a, acc[b]);
        }
    }
    // K tail (300 -> 12, 207 -> 15)
    const int krem = K - nfull * 32;
    if (krem > 0) {
        const int k0 = nfull * 32;
        __syncthreads();
        #pragma unroll
        for (int p = 0; p < 4; ++p) {
            int r = p * 16 + srow;
            #pragma unroll
            for (int q = 0; q < 4; ++q) {
                int k = skg * 4 + q;
                float v = 0.f;
                if (k < krem && row0 + r < NM)
                    v = A[(size_t)(row0 + r) * K + k0 + k];
                As[r * 33 + k] = v;
            }
        }
        __syncthreads();
        for (int k = 0; k < krem; ++k) {
            float a = As[lrow * 33 + k];
            const float* Bk = Bt + (size_t)(k0 + k) * 64 + half * 32;
            #pragma unroll
            for (int b = 0; b < 32; ++b) acc[b] = fmaf(Bk[b], a, acc[b]);
        }
    }

    if (row >= NM) return;
    if constexpr (MODE == 0) {
        float t0 = add[row];
        float* dst = C + (size_t)row * 64 + half * 32;   // 128B line per thread
        #pragma unroll
        for (int q = 0; q < 8; ++q) {
            float4 v = {acc[q*4+0] + t0, acc[q*4+1] + t0, acc[q*4+2] + t0, acc[q*4+3] + t0};
            *(float4*)(dst + q * 4) = v;
        }
    } else {
        const float* av = add + (size_t)row * 64 + half * 32;
        #pragma unroll
        for (int b = 0; b < 32; ++b)   // lanes = consecutive rows -> coalesced stores
            C[(size_t)(half * 32 + b) * NM + row] = acc[b] + av[b];
    }
}

// J[b][j][d] += sum_v Jr[j][v] * vs[v*3+d][b]   (vs is [NM][64])
// v2: latency-bound fix. 250 blocks x 8 waves; each wave owns a 25-vertex chunk
// and ALL 24 joints (acc[24][3] = 72 indep FMA chains per 3 loads -> ILP).
// Cross-wave reduce via LDS slices (pitch 73 -> conflict-free), then one
// atomicAdd per output per block (same global atomic count as v1).
__global__ __launch_bounds__(512)
void jreduce_kernel(const float* __restrict__ vs, const float* __restrict__ Jr,
                    float* J)
{
    __shared__ float Ls[4][64][73];     // 74.75 KB
    const int t = threadIdx.x;
    const int b = t & 63;
    const int w = __builtin_amdgcn_readfirstlane(t >> 6);   // wave id 0..7 (uniform)

    float acc[24][3];
    #pragma unroll
    for (int j = 0; j < 24; ++j) { acc[j][0]=0.f; acc[j][1]=0.f; acc[j][2]=0.f; }

    const int v0 = blockIdx.x * 200 + w * 25;
    #pragma unroll 5
    for (int v = v0; v < v0 + 25; ++v) {
        float p0 = vs[(size_t)(v*3+0)*64 + b];     // coalesced 256B/wave
        float p1 = vs[(size_t)(v*3+1)*64 + b];
        float p2 = vs[(size_t)(v*3+2)*64 + b];
        #pragma unroll
        for (int j = 0; j < 24; ++j) {
            float r = Jr[(size_t)j*NV + v];        // wave-uniform -> s_load
            acc[j][0] += r*p0; acc[j][1] += r*p1; acc[j][2] += r*p2;
        }
    }

    // waves 0-3 write their slice; waves 4-7 add into slice w-4 (disjoint -> no race)
    if (w < 4) {
        float* d = Ls[w][b];
        #pragma unroll
        for (int j = 0; j < 24; ++j) {
            d[j*3+0] = acc[j][0]; d[j*3+1] = acc[j][1]; d[j*3+2] = acc[j][2];
        }
    }
    __syncthreads();
    if (w >= 4) {
        float* d = Ls[w-4][b];
        #pragma unroll
        for (int j = 0; j < 24; ++j) {
            d[j*3+0] += acc[j][0]; d[j*3+1] += acc[j][1]; d[j*3+2] += acc[j][2];
        }
    }
    __syncthreads();

    // 4608 outputs, 512 threads -> 9 each; sum the 4 slices, one atomic each
    #pragma unroll
    for (int q = 0; q < 9; ++q) {
        int oid = t * 9 + q;
        int bb = oid / 72, c = oid - bb * 72;
        float s = Ls[0][bb][c] + Ls[1][bb][c] + Ls[2][bb][c] + Ls[3][bb][c];
        atomicAdd(&J[(size_t)bb * 72 + c], s);
    }
}

// per-(b,j): rodrigues -> R; lrotT [207][64]; level-parallel kinematic chain; G' [64][24][12]
__global__ __launch_bounds__(192)
void pose_kernel(const float* __restrict__ pose, const float* __restrict__ J,
                 float* __restrict__ G, float* __restrict__ lrotT)
{
    __shared__ float Gl[8][24][12];
    __shared__ float Gc[8][24][12];
    const int t  = threadIdx.x;
    const int bl = t / 24;
    const int j  = t % 24;
    const int b  = blockIdx.x * 8 + bl;

    float tx = pose[b*72 + j*3 + 0];
    float ty = pose[b*72 + j*3 + 1];
    float tz = pose[b*72 + j*3 + 2];
    float ax = tx + 1e-8f, ay = ty + 1e-8f, az = tz + 1e-8f;
    float angle = sqrtf(ax*ax + ay*ay + az*az);
    float nx = tx / angle, ny = ty / angle, nz = tz / angle;
    float half = 0.5f * angle;
    float sw = sinf(half);
    float qw = cosf(half), qx = sw*nx, qy = sw*ny, qz = sw*nz;
    float qn = sqrtf(qw*qw + qx*qx + qy*qy + qz*qz);
    qw /= qn; qx /= qn; qy /= qn; qz /= qn;
    float w2=qw*qw, x2=qx*qx, y2=qy*qy, z2=qz*qz;
    float xy=qx*qy, xz=qx*qz, yz=qy*qz, wx=qw*qx, wy=qw*qy, wz=qw*qz;
    float r00 = w2+x2-y2-z2, r01 = 2.f*(xy-wz), r02 = 2.f*(wy+xz);
    float r10 = 2.f*(wz+xy), r11 = w2-x2+y2-z2, r12 = 2.f*(yz-wx);
    float r20 = 2.f*(xz-wy), r21 = 2.f*(wx+yz), r22 = w2-x2-y2+z2;

    if (j >= 1) {   // lrotT[k][b], k = (j-1)*9 + c
        const int k9 = (j-1)*9;
        lrotT[(size_t)(k9+0)*64+b]=r00-1.f; lrotT[(size_t)(k9+1)*64+b]=r01;
        lrotT[(size_t)(k9+2)*64+b]=r02;     lrotT[(size_t)(k9+3)*64+b]=r10;
        lrotT[(size_t)(k9+4)*64+b]=r11-1.f; lrotT[(size_t)(k9+5)*64+b]=r12;
        lrotT[(size_t)(k9+6)*64+b]=r20;     lrotT[(size_t)(k9+7)*64+b]=r21;
        lrotT[(size_t)(k9+8)*64+b]=r22-1.f;
    }
    float jx = J[(size_t)(b*24+j)*3+0];
    float jy = J[(size_t)(b*24+j)*3+1];
    float jz = J[(size_t)(b*24+j)*3+2];
    float rx = jx, ry = jy, rz = jz;
    if (j > 0) {
        int p = c_par[j];
        rx -= J[(size_t)(b*24+p)*3+0];
        ry -= J[(size_t)(b*24+p)*3+1];
        rz -= J[(size_t)(b*24+p)*3+2];
    }
    float* gl = Gl[bl][j];
    gl[0]=r00; gl[1]=r01; gl[2]=r02;  gl[3]=rx;
    gl[4]=r10; gl[5]=r11; gl[6]=r12;  gl[7]=ry;
    gl[8]=r20; gl[9]=r21; gl[10]=r22; gl[11]=rz;
    __syncthreads();

    if (j == 0) {
        #pragma unroll
        for (int c = 0; c < 12; ++c) Gc[bl][0][c] = Gl[bl][0][c];
    }
    const int dj = c_depth[j];
    for (int lvl = 1; lvl <= 8; ++lvl) {
        __syncthreads();
        if (dj == lvl) {
            const float* Aa = Gc[bl][c_par[j]];
            const float* Bb = Gl[bl][j];
            float* D = Gc[bl][j];
            #pragma unroll
            for (int r = 0; r < 3; ++r) {
                float a0=Aa[r*4+0], a1=Aa[r*4+1], a2=Aa[r*4+2], a3=Aa[r*4+3];
                D[r*4+0] = a0*Bb[0] + a1*Bb[4] + a2*Bb[8];
                D[r*4+1] = a0*Bb[1] + a1*Bb[5] + a2*Bb[9];
                D[r*4+2] = a0*Bb[2] + a1*Bb[6] + a2*Bb[10];
                D[r*4+3] = a0*Bb[3] + a1*Bb[7] + a2*Bb[11] + a3;
            }
        }
    }
    __syncthreads();

    const float* Gi = Gc[bl][j];
    float* go = G + (size_t)(b*24 + j) * 12;
    #pragma unroll
    for (int r = 0; r < 3; ++r) {
        go[r*4+0] = Gi[r*4+0];
        go[r*4+1] = Gi[r*4+1];
        go[r*4+2] = Gi[r*4+2];
        go[r*4+3] = Gi[r*4+3] - (Gi[r*4+0]*jx + Gi[r*4+1]*jy + Gi[r*4+2]*jz);
    }
}

// out[b][v][d] = sum_j w[v][j] * (G'[b][j] applied to vp[b][v])
__global__ __launch_bounds__(256)
void skin_kernel(const float* __restrict__ vp, const float* __restrict__ G,
                 const float* __restrict__ wts, float* __restrict__ out)
{
    const int v = blockIdx.x * 256 + threadIdx.x;
    if (v >= NV) return;
    const int b0 = blockIdx.y * 8;
    float w[24];
    const float4* wp = (const float4*)(wts + (size_t)v * 24);
    #pragma unroll
    for (int q = 0; q < 6; ++q) {
        float4 t = wp[q];
        w[q*4+0]=t.x; w[q*4+1]=t.y; w[q*4+2]=t.z; w[q*4+3]=t.w;
    }
    for (int b = b0; b < b0 + 8; ++b) {
        const float* pb = vp + (size_t)b * NM + v*3;
        float px = pb[0], py = pb[1], pz = pb[2];
        float ox = 0.f, oy = 0.f, oz = 0.f;
        const float* Gb = G + (size_t)b * 24 * 12;
        #pragma unroll
        for (int j = 0; j < 24; ++j) {
            const float* g = Gb + j*12;   // uniform -> s_load
            float wj = w[j];
            ox += wj * (g[0]*px + g[1]*py + g[2]*pz  + g[3]);
            oy += wj * (g[4]*px + g[5]*py + g[6]*pz  + g[7]);
            oz += wj * (g[8]*px + g[9]*py + g[10]*pz + g[11]);
        }
        float* ob = out + (size_t)b * NM + v*3;
        ob[0] = ox; ob[1] = oy; ob[2] = oz;
    }
}

extern "C" void kernel_launch(void* const* d_in, const int* in_sizes, int n_in,
                              void* d_out, int out_size, void* d_ws, size_t ws_size,
                              hipStream_t stream) {
    const float* pose       = (const float*)d_in[0];
    const float* beta       = (const float*)d_in[1];
    const float* v_template = (const float*)d_in[2];
    const float* shapedirs  = (const float*)d_in[3];
    const float* posedirs   = (const float*)d_in[4];
    const float* Jreg       = (const float*)d_in[5];
    const float* weights    = (const float*)d_in[6];
    float* out = (float*)d_out;

    char* ws = (char*)d_ws;
    float* vs_ws    = (float*)(ws);                 // [NM][64]  38.4 MB
    float* vp_ws    = (float*)(ws + 38400000);      // [64][NM]  38.4 MB
    float* betaT_ws = (float*)(ws + 38400000);      // [300][64] aliases vp (dead before gemm2)
    float* J_ws     = (float*)(ws + 76800000);      // [64][24][3]
    float* G_ws     = (float*)(ws + 76818432);      // [64][24][12]
    float* lrotT_ws = (float*)(ws + 76892160);      // [207][64]

    prep_kernel<<<75, 256, 0, stream>>>(beta, betaT_ws, J_ws);
    gemm_kernel<300, 0><<<2344, 128, 0, stream>>>(shapedirs, betaT_ws, v_template, vs_ws);
    jreduce_kernel<<<250, 512, 0, stream>>>(vs_ws, Jreg, J_ws);
    pose_kernel<<<8, 192, 0, stream>>>(pose, J_ws, G_ws, lrotT_ws);
    gemm_kernel<207, 1><<<2344, 128, 0, stream>>>(posedirs, lrotT_ws, vs_ws, vp_ws);
    skin_kernel<<<dim3(196, 8), 256, 0, stream>>>(vp_ws, G_ws, weights, out);
}

// Round 2
// 606.279 us; speedup vs baseline: 1.1701x; 1.0364x over previous
//
#include <hip/hip_runtime.h>
#include <math.h>

#define NV 50000
#define NM 150000   // 50000*3 rows

typedef float  f32x4  __attribute__((ext_vector_type(4)));
typedef __bf16 bf16x8 __attribute__((ext_vector_type(8)));
// 4-byte-aligned float4 (K=207 rows are only dword-aligned)
typedef float  f4u    __attribute__((ext_vector_type(4), aligned(4)));

// par[j] for j in 0..23 (par[0] unused); depth[j] = chain depth
__constant__ int c_par[24]   = {0, 0,0,0, 1,2,3, 4,5,6, 7,8,9,9,9, 12,13,14, 16,17, 18,19, 20,21};
__constant__ int c_depth[24] = {0, 1,1,1, 2,2,2, 3,3,3, 4,4,4,4,4, 5,5,5, 6,6, 7,7, 8,8};

// transpose beta [64][300] -> betaT [300][64]; zero J [64][24][3]
__global__ __launch_bounds__(256)
void prep_kernel(const float* __restrict__ beta, float* __restrict__ betaT,
                 float* __restrict__ J)
{
    int i = blockIdx.x * 256 + threadIdx.x;
    if (i < 300 * 64) {
        int k = i >> 6, b = i & 63;
        betaT[i] = beta[b * 300 + k];
    }
    if (i < 64 * 24 * 3) J[i] = 0.f;
}

// bf16-MFMA tall-skinny GEMM: C = A[NM x K] * Bt[K x 64] (+ add), fp32 in/out.
// Block = 512 thr (8 waves), 128 rows; wave w owns rows row0+w*16..+16, all 64 batch.
// A fragments: direct global->reg (8 consecutive fp32/lane, 2x dwordx4), cvt bf16.
// B: staged once/block to LDS transposed Bs[n][k] bf16 (pitch PB: 2-way banks, 16B align).
// MODE0: D[row][b], store C[row*64+b], add = v_template[row] broadcast.
// MODE1: operands swapped (M=batch, N=rows) -> D[b][row], store C[b*NM+row] coalesced,
//        add = vs[row*64+b] read as 4 float4/lane (full-64B-line pattern).
template<int K, int MODE>
__global__ __launch_bounds__(512)
void gemm_mfma(const float* __restrict__ A, const float* __restrict__ Bt,
               const float* __restrict__ add, float* __restrict__ C)
{
    constexpr int NFULL = K / 32;            // 9 (K=300), 6 (K=207)
    constexpr int NC    = (K + 31) / 32;     // 10, 7
    constexpr int PB    = NC * 32 + 8;       // 328, 232  (mod 8 == 0 -> 16B-aligned b128)
    __shared__ __bf16 Bs[64 * PB];           // 41.0 KB / 29.0 KB

    const int t    = threadIdx.x;
    const int row0 = blockIdx.x * 128;
    const int w    = __builtin_amdgcn_readfirstlane(t >> 6);   // wave 0..7
    const int l    = t & 63;
    const int lr   = l & 15;                 // frag M/N lane index
    const int kb   = l >> 4;                 // k sub-block 0..3

    // ---- stage Bt -> Bs[n][k] bf16, zero-padded to NC*32 ----
    for (int i = t; i < 64 * NC * 32; i += 512) {
        int k = i >> 6, n = i & 63;
        float v = (k < K) ? Bt[(size_t)k * 64 + n] : 0.f;
        Bs[n * PB + k] = (__bf16)v;
    }
    __syncthreads();

    // ---- main: per-wave 16 rows x 64 batch, chunk-prefetched A frags ----
    const int grow = row0 + w * 16 + lr;               // this lane's A row
    const int arow = grow < NM ? grow : NM - 1;        // clamp (stores are guarded)
    const float* Arow = A + (size_t)arow * K;

    f32x4 acc[4] = {};
    float cur[8], nxt[8];
    {
        f4u p0 = *(const f4u*)(Arow + kb * 8);
        f4u p1 = *(const f4u*)(Arow + kb * 8 + 4);
        cur[0]=p0.x; cur[1]=p0.y; cur[2]=p0.z; cur[3]=p0.w;
        cur[4]=p1.x; cur[5]=p1.y; cur[6]=p1.z; cur[7]=p1.w;
    }
    #pragma unroll
    for (int c = 0; c < NC; ++c) {
        if (c + 1 < NC) {
            const int kn = (c + 1) * 32 + kb * 8;
            if (c + 1 < NFULL) {
                f4u p0 = *(const f4u*)(Arow + kn);
                f4u p1 = *(const f4u*)(Arow + kn + 4);
                nxt[0]=p0.x; nxt[1]=p0.y; nxt[2]=p0.z; nxt[3]=p0.w;
                nxt[4]=p1.x; nxt[5]=p1.y; nxt[6]=p1.z; nxt[7]=p1.w;
            } else {                      // tail chunk: guarded elementwise
                #pragma unroll
                for (int e = 0; e < 8; ++e)
                    nxt[e] = (kn + e < K) ? Arow[kn + e] : 0.f;
            }
        }
        bf16x8 af;
        #pragma unroll
        for (int e = 0; e < 8; ++e) af[e] = (__bf16)cur[e];
        #pragma unroll
        for (int n = 0; n < 4; ++n) {
            const bf16x8 bfv = *(const bf16x8*)(Bs + (n * 16 + lr) * PB + c * 32 + kb * 8);
            if constexpr (MODE == 0)
                acc[n] = __builtin_amdgcn_mfma_f32_16x16x32_bf16(af, bfv, acc[n], 0, 0, 0);
            else
                acc[n] = __builtin_amdgcn_mfma_f32_16x16x32_bf16(bfv, af, acc[n], 0, 0, 0);
        }
        #pragma unroll
        for (int e = 0; e < 8; ++e) cur[e] = nxt[e];
    }

    // ---- epilogue (NM % 16 == 0 -> validity is whole-wave) ----
    if (row0 + w * 16 >= NM) return;
    if constexpr (MODE == 0) {
        // D: row = kb*4+r (local), col b = n*16+lr
        f4u ta = *(const f4u*)(add + row0 + w * 16 + kb * 4);
        #pragma unroll
        for (int n = 0; n < 4; ++n)
            #pragma unroll
            for (int r = 0; r < 4; ++r)
                C[(size_t)(row0 + w * 16 + kb * 4 + r) * 64 + n * 16 + lr] = acc[n][r] + ta[r];
    } else {
        // D: b = m*16+kb*4+r, vrow = row0+w*16+lr
        const size_t vrow = row0 + w * 16 + lr;
        #pragma unroll
        for (int m = 0; m < 4; ++m) {
            f4u av = *(const f4u*)(add + vrow * 64 + m * 16 + kb * 4);
            #pragma unroll
            for (int r = 0; r < 4; ++r)
                C[(size_t)(m * 16 + kb * 4 + r) * NM + vrow] = acc[m][r] + av[r];
        }
    }
}

// J[b][j][d] += sum_v Jr[j][v] * vs[v*3+d][b]   (vs is [NM][64])
__global__ __launch_bounds__(512)
void jreduce_kernel(const float* __restrict__ vs, const float* __restrict__ Jr,
                    float* J)
{
    __shared__ float Ls[4][64][73];     // 74.75 KB
    const int t = threadIdx.x;
    const int b = t & 63;
    const int w = __builtin_amdgcn_readfirstlane(t >> 6);   // wave id 0..7 (uniform)

    float acc[24][3];
    #pragma unroll
    for (int j = 0; j < 24; ++j) { acc[j][0]=0.f; acc[j][1]=0.f; acc[j][2]=0.f; }

    const int v0 = blockIdx.x * 200 + w * 25;
    #pragma unroll 5
    for (int v = v0; v < v0 + 25; ++v) {
        float p0 = vs[(size_t)(v*3+0)*64 + b];     // coalesced 256B/wave
        float p1 = vs[(size_t)(v*3+1)*64 + b];
        float p2 = vs[(size_t)(v*3+2)*64 + b];
        #pragma unroll
        for (int j = 0; j < 24; ++j) {
            float r = Jr[(size_t)j*NV + v];        // wave-uniform -> s_load
            acc[j][0] += r*p0; acc[j][1] += r*p1; acc[j][2] += r*p2;
        }
    }

    // waves 0-3 write their slice; waves 4-7 add into slice w-4 (disjoint -> no race)
    if (w < 4) {
        float* d = Ls[w][b];
        #pragma unroll
        for (int j = 0; j < 24; ++j) {
            d[j*3+0] = acc[j][0]; d[j*3+1] = acc[j][1]; d[j*3+2] = acc[j][2];
        }
    }
    __syncthreads();
    if (w >= 4) {
        float* d = Ls[w-4][b];
        #pragma unroll
        for (int j = 0; j < 24; ++j) {
            d[j*3+0] += acc[j][0]; d[j*3+1] += acc[j][1]; d[j*3+2] += acc[j][2];
        }
    }
    __syncthreads();

    // 4608 outputs, 512 threads -> 9 each; sum the 4 slices, one atomic each
    #pragma unroll
    for (int q = 0; q < 9; ++q) {
        int oid = t * 9 + q;
        int bb = oid / 72, c = oid - bb * 72;
        float s = Ls[0][bb][c] + Ls[1][bb][c] + Ls[2][bb][c] + Ls[3][bb][c];
        atomicAdd(&J[(size_t)bb * 72 + c], s);
    }
}

// per-(b,j): rodrigues -> R; lrotT [207][64]; level-parallel kinematic chain; G' [64][24][12]
__global__ __launch_bounds__(192)
void pose_kernel(const float* __restrict__ pose, const float* __restrict__ J,
                 float* __restrict__ G, float* __restrict__ lrotT)
{
    __shared__ float Gl[8][24][12];
    __shared__ float Gc[8][24][12];
    const int t  = threadIdx.x;
    const int bl = t / 24;
    const int j  = t % 24;
    const int b  = blockIdx.x * 8 + bl;

    float tx = pose[b*72 + j*3 + 0];
    float ty = pose[b*72 + j*3 + 1];
    float tz = pose[b*72 + j*3 + 2];
    float ax = tx + 1e-8f, ay = ty + 1e-8f, az = tz + 1e-8f;
    float angle = sqrtf(ax*ax + ay*ay + az*az);
    float nx = tx / angle, ny = ty / angle, nz = tz / angle;
    float half = 0.5f * angle;
    float sw = sinf(half);
    float qw = cosf(half), qx = sw*nx, qy = sw*ny, qz = sw*nz;
    float qn = sqrtf(qw*qw + qx*qx + qy*qy + qz*qz);
    qw /= qn; qx /= qn; qy /= qn; qz /= qn;
    float w2=qw*qw, x2=qx*qx, y2=qy*qy, z2=qz*qz;
    float xy=qx*qy, xz=qx*qz, yz=qy*qz, wx=qw*qx, wy=qw*qy, wz=qw*qz;
    float r00 = w2+x2-y2-z2, r01 = 2.f*(xy-wz), r02 = 2.f*(wy+xz);
    float r10 = 2.f*(wz+xy), r11 = w2-x2+y2-z2, r12 = 2.f*(yz-wx);
    float r20 = 2.f*(xz-wy), r21 = 2.f*(wx+yz), r22 = w2-x2-y2+z2;

    if (j >= 1) {   // lrotT[k][b], k = (j-1)*9 + c
        const int k9 = (j-1)*9;
        lrotT[(size_t)(k9+0)*64+b]=r00-1.f; lrotT[(size_t)(k9+1)*64+b]=r01;
        lrotT[(size_t)(k9+2)*64+b]=r02;     lrotT[(size_t)(k9+3)*64+b]=r10;
        lrotT[(size_t)(k9+4)*64+b]=r11-1.f; lrotT[(size_t)(k9+5)*64+b]=r12;
        lrotT[(size_t)(k9+6)*64+b]=r20;     lrotT[(size_t)(k9+7)*64+b]=r21;
        lrotT[(size_t)(k9+8)*64+b]=r22-1.f;
    }
    float jx = J[(size_t)(b*24+j)*3+0];
    float jy = J[(size_t)(b*24+j)*3+1];
    float jz = J[(size_t)(b*24+j)*3+2];
    float rx = jx, ry = jy, rz = jz;
    if (j > 0) {
        int p = c_par[j];
        rx -= J[(size_t)(b*24+p)*3+0];
        ry -= J[(size_t)(b*24+p)*3+1];
        rz -= J[(size_t)(b*24+p)*3+2];
    }
    float* gl = Gl[bl][j];
    gl[0]=r00; gl[1]=r01; gl[2]=r02;  gl[3]=rx;
    gl[4]=r10; gl[5]=r11; gl[6]=r12;  gl[7]=ry;
    gl[8]=r20; gl[9]=r21; gl[10]=r22; gl[11]=rz;
    __syncthreads();

    if (j == 0) {
        #pragma unroll
        for (int c = 0; c < 12; ++c) Gc[bl][0][c] = Gl[bl][0][c];
    }
    const int dj = c_depth[j];
    for (int lvl = 1; lvl <= 8; ++lvl) {
        __syncthreads();
        if (dj == lvl) {
            const float* Aa = Gc[bl][c_par[j]];
            const float* Bb = Gl[bl][j];
            float* D = Gc[bl][j];
            #pragma unroll
            for (int r = 0; r < 3; ++r) {
                float a0=Aa[r*4+0], a1=Aa[r*4+1], a2=Aa[r*4+2], a3=Aa[r*4+3];
                D[r*4+0] = a0*Bb[0] + a1*Bb[4] + a2*Bb[8];
                D[r*4+1] = a0*Bb[1] + a1*Bb[5] + a2*Bb[9];
                D[r*4+2] = a0*Bb[2] + a1*Bb[6] + a2*Bb[10];
                D[r*4+3] = a0*Bb[3] + a1*Bb[7] + a2*Bb[11] + a3;
            }
        }
    }
    __syncthreads();

    const float* Gi = Gc[bl][j];
    float* go = G + (size_t)(b*24 + j) * 12;
    #pragma unroll
    for (int r = 0; r < 3; ++r) {
        go[r*4+0] = Gi[r*4+0];
        go[r*4+1] = Gi[r*4+1];
        go[r*4+2] = Gi[r*4+2];
        go[r*4+3] = Gi[r*4+3] - (Gi[r*4+0]*jx + Gi[r*4+1]*jy + Gi[r*4+2]*jz);
    }
}

// out[b][v][d] = sum_j w[v][j] * (G'[b][j] applied to vp[b][v])
__global__ __launch_bounds__(256)
void skin_kernel(const float* __restrict__ vp, const float* __restrict__ G,
                 const float* __restrict__ wts, float* __restrict__ out)
{
    const int v = blockIdx.x * 256 + threadIdx.x;
    if (v >= NV) return;
    const int b0 = blockIdx.y * 8;
    float w[24];
    const float4* wp = (const float4*)(wts + (size_t)v * 24);
    #pragma unroll
    for (int q = 0; q < 6; ++q) {
        float4 t = wp[q];
        w[q*4+0]=t.x; w[q*4+1]=t.y; w[q*4+2]=t.z; w[q*4+3]=t.w;
    }
    for (int b = b0; b < b0 + 8; ++b) {
        const float* pb = vp + (size_t)b * NM + v*3;
        float px = pb[0], py = pb[1], pz = pb[2];
        float ox = 0.f, oy = 0.f, oz = 0.f;
        const float* Gb = G + (size_t)b * 24 * 12;
        #pragma unroll
        for (int j = 0; j < 24; ++j) {
            const float* g = Gb + j*12;   // uniform -> s_load
            float wj = w[j];
            ox += wj * (g[0]*px + g[1]*py + g[2]*pz  + g[3]);
            oy += wj * (g[4]*px + g[5]*py + g[6]*pz  + g[7]);
            oz += wj * (g[8]*px + g[9]*py + g[10]*pz + g[11]);
        }
        float* ob = out + (size_t)b * NM + v*3;
        ob[0] = ox; ob[1] = oy; ob[2] = oz;
    }
}

extern "C" void kernel_launch(void* const* d_in, const int* in_sizes, int n_in,
                              void* d_out, int out_size, void* d_ws, size_t ws_size,
                              hipStream_t stream) {
    const float* pose       = (const float*)d_in[0];
    const float* beta       = (const float*)d_in[1];
    const float* v_template = (const float*)d_in[2];
    const float* shapedirs  = (const float*)d_in[3];
    const float* posedirs   = (const float*)d_in[4];
    const float* Jreg       = (const float*)d_in[5];
    const float* weights    = (const float*)d_in[6];
    float* out = (float*)d_out;

    char* ws = (char*)d_ws;
    float* vs_ws    = (float*)(ws);                 // [NM][64]  38.4 MB
    float* vp_ws    = (float*)(ws + 38400000);      // [64][NM]  38.4 MB
    float* betaT_ws = (float*)(ws + 38400000);      // [300][64] aliases vp (dead before gemm2)
    float* J_ws     = (float*)(ws + 76800000);      // [64][24][3]
    float* G_ws     = (float*)(ws + 76818432);      // [64][24][12]
    float* lrotT_ws = (float*)(ws + 76892160);      // [207][64]

    prep_kernel<<<75, 256, 0, stream>>>(beta, betaT_ws, J_ws);
    gemm_mfma<300, 0><<<1172, 512, 0, stream>>>(shapedirs, betaT_ws, v_template, vs_ws);
    jreduce_kernel<<<250, 512, 0, stream>>>(vs_ws, Jreg, J_ws);
    pose_kernel<<<8, 192, 0, stream>>>(pose, J_ws, G_ws, lrotT_ws);
    gemm_mfma<207, 1><<<1172, 512, 0, stream>>>(posedirs, lrotT_ws, vs_ws, vp_ws);
    skin_kernel<<<dim3(196, 8), 256, 0, stream>>>(vp_ws, G_ws, weights, out);
}

// Round 3
// 572.120 us; speedup vs baseline: 1.2400x; 1.0597x over previous
//
#include <hip/hip_runtime.h>
#include <math.h>

#define NV 50000
#define NM 150000   // 50000*3 rows

typedef float  f32x4  __attribute__((ext_vector_type(4)));
typedef __bf16 bf16x8 __attribute__((ext_vector_type(8)));
// 4-byte-aligned float4 (K=207 rows are only dword-aligned)
typedef float  f4u    __attribute__((ext_vector_type(4), aligned(4)));

// par[j] for j in 0..23 (par[0] unused); depth[j] = chain depth
__constant__ int c_par[24]   = {0, 0,0,0, 1,2,3, 4,5,6, 7,8,9,9,9, 12,13,14, 16,17, 18,19, 20,21};
__constant__ int c_depth[24] = {0, 1,1,1, 2,2,2, 3,3,3, 4,4,4,4,4, 5,5,5, 6,6, 7,7, 8,8};

// transpose beta [64][300] -> betaT [300][64]; zero J [64][24][3]
__global__ __launch_bounds__(256)
void prep_kernel(const float* __restrict__ beta, float* __restrict__ betaT,
                 float* __restrict__ J)
{
    int i = blockIdx.x * 256 + threadIdx.x;
    if (i < 300 * 64) {
        int k = i >> 6, b = i & 63;
        betaT[i] = beta[b * 300 + k];
    }
    if (i < 64 * 24 * 3) J[i] = 0.f;
}

// bf16-MFMA tall-skinny GEMM: C = A[NM x K] * Bt[K x 64] (+ add), fp32 in/out.
// v3 (latency fix): ALL of a lane's A row (20 x f4u/guarded-scalar loads) issued
// up-front -> ~20 outstanding VMEM/wave (Little's law: was 2 -> 1.2 TB/s).
// B staging: coalesced 256B row loads + packed b128 LDS writes (was scalar bf16
// writes at 656B stride = 8-way bank conflict, 3.75M cycles).
// MODE0: D[row][b], store C[row*64+b], add = v_template[row] broadcast.
// MODE1: operands swapped (M=batch, N=rows) -> D[b][row], coalesced stores.
template<int K, int MODE>
__global__ __launch_bounds__(512, 4)   // force VGPR<=128 -> 2 blocks/CU
void gemm_mfma(const float* __restrict__ A, const float* __restrict__ Bt,
               const float* __restrict__ add, float* __restrict__ C)
{
    constexpr int NFULL = K / 32;            // 9 (K=300), 6 (K=207)
    constexpr int KTAIL = K - NFULL * 32;    // 12, 15
    constexpr int NC    = NFULL + 1;         // 10, 7
    constexpr int PB    = NC * 32 + 8;       // 328, 232  (x2B: 656/464, mod16=0)
    __shared__ __bf16 Bs[64 * PB];           // 41.0 KB / 29.0 KB

    const int t    = threadIdx.x;
    const int row0 = blockIdx.x * 128;
    const int w    = __builtin_amdgcn_readfirstlane(t >> 6);   // wave 0..7
    const int l    = t & 63;
    const int lr   = l & 15;                 // frag M/N lane index
    const int kb   = l >> 4;                 // k sub-block 0..3

    // ---- stage Bt[K][64] -> Bs[n][k] bf16 (zero-pad k>=K) ----
    // task = (n, 8k-block): 8 coalesced 256B loads, 1 ds_write_b128.
    constexpr int NTASK = 64 * NC * 4;       // 2560 / 1792
    #pragma unroll
    for (int s = 0; s < (NTASK + 511) / 512; ++s) {
        const int id = t + s * 512;
        if (id < NTASK) {
            const int n  = id & 63;
            const int k8 = (id >> 6) * 8;
            float v[8];
            #pragma unroll
            for (int e = 0; e < 8; ++e) {
                int k = k8 + e;
                v[e] = (k < K) ? Bt[(size_t)k * 64 + n] : 0.f;
            }
            bf16x8 bv;
            #pragma unroll
            for (int e = 0; e < 8; ++e) bv[e] = (__bf16)v[e];
            *(bf16x8*)(Bs + n * PB + k8) = bv;   // 16B-aligned, bank-uniform
        }
    }
    __syncthreads();

    // grid covers 150016 rows; NM%16==0 -> whole-wave validity
    if (row0 + w * 16 >= NM) return;
    const int grow = row0 + w * 16 + lr;
    const float* Arow = A + (size_t)grow * K;

    // ---- issue ALL A loads up-front (no serial chunk dependency) ----
    f4u a[2 * NC];
    #pragma unroll
    for (int c = 0; c < NFULL; ++c) {
        a[2*c]   = *(const f4u*)(Arow + c * 32 + kb * 8);
        a[2*c+1] = *(const f4u*)(Arow + c * 32 + kb * 8 + 4);
    }
    {   // tail chunk: guarded per-element (avoids OOB past array end)
        float tv[8];
        #pragma unroll
        for (int e = 0; e < 8; ++e) {
            int k = NFULL * 32 + kb * 8 + e;
            tv[e] = (k < K) ? Arow[k] : 0.f;
        }
        a[2*NFULL]   = (f4u){tv[0], tv[1], tv[2], tv[3]};
        a[2*NFULL+1] = (f4u){tv[4], tv[5], tv[6], tv[7]};
    }

    // ---- MFMA main: compiler emits counted vmcnt per chunk ----
    f32x4 acc[4] = {};
    #pragma unroll
    for (int c = 0; c < NC; ++c) {
        bf16x8 af;
        #pragma unroll
        for (int e = 0; e < 4; ++e) {
            af[e]     = (__bf16)a[2*c][e];
            af[4 + e] = (__bf16)a[2*c+1][e];
        }
        #pragma unroll
        for (int n = 0; n < 4; ++n) {
            const bf16x8 bfv = *(const bf16x8*)(Bs + (n * 16 + lr) * PB + c * 32 + kb * 8);
            if constexpr (MODE == 0)
                acc[n] = __builtin_amdgcn_mfma_f32_16x16x32_bf16(af, bfv, acc[n], 0, 0, 0);
            else
                acc[n] = __builtin_amdgcn_mfma_f32_16x16x32_bf16(bfv, af, acc[n], 0, 0, 0);
        }
    }

    // ---- epilogue ----
    if constexpr (MODE == 0) {
        // D: local row = kb*4+r, col b = n*16+lr
        f4u ta = *(const f4u*)(add + row0 + w * 16 + kb * 4);
        #pragma unroll
        for (int n = 0; n < 4; ++n)
            #pragma unroll
            for (int r = 0; r < 4; ++r)
                C[(size_t)(row0 + w * 16 + kb * 4 + r) * 64 + n * 16 + lr] = acc[n][r] + ta[r];
    } else {
        // D: b = m*16+kb*4+r, vrow = row0+w*16+lr
        const size_t vrow = row0 + w * 16 + lr;
        #pragma unroll
        for (int m = 0; m < 4; ++m) {
            f4u av = *(const f4u*)(add + vrow * 64 + m * 16 + kb * 4);
            #pragma unroll
            for (int r = 0; r < 4; ++r)
                C[(size_t)(m * 16 + kb * 4 + r) * NM + vrow] = acc[m][r] + av[r];
        }
    }
}

// J[b][j][d] += sum_v Jr[j][v] * vs[v*3+d][b]   (vs is [NM][64])
__global__ __launch_bounds__(512)
void jreduce_kernel(const float* __restrict__ vs, const float* __restrict__ Jr,
                    float* J)
{
    __shared__ float Ls[4][64][73];     // 74.75 KB
    const int t = threadIdx.x;
    const int b = t & 63;
    const int w = __builtin_amdgcn_readfirstlane(t >> 6);   // wave id 0..7 (uniform)

    float acc[24][3];
    #pragma unroll
    for (int j = 0; j < 24; ++j) { acc[j][0]=0.f; acc[j][1]=0.f; acc[j][2]=0.f; }

    const int v0 = blockIdx.x * 200 + w * 25;
    #pragma unroll 5
    for (int v = v0; v < v0 + 25; ++v) {
        float p0 = vs[(size_t)(v*3+0)*64 + b];     // coalesced 256B/wave
        float p1 = vs[(size_t)(v*3+1)*64 + b];
        float p2 = vs[(size_t)(v*3+2)*64 + b];
        #pragma unroll
        for (int j = 0; j < 24; ++j) {
            float r = Jr[(size_t)j*NV + v];        // wave-uniform -> s_load
            acc[j][0] += r*p0; acc[j][1] += r*p1; acc[j][2] += r*p2;
        }
    }

    // waves 0-3 write their slice; waves 4-7 add into slice w-4 (disjoint -> no race)
    if (w < 4) {
        float* d = Ls[w][b];
        #pragma unroll
        for (int j = 0; j < 24; ++j) {
            d[j*3+0] = acc[j][0]; d[j*3+1] = acc[j][1]; d[j*3+2] = acc[j][2];
        }
    }
    __syncthreads();
    if (w >= 4) {
        float* d = Ls[w-4][b];
        #pragma unroll
        for (int j = 0; j < 24; ++j) {
            d[j*3+0] += acc[j][0]; d[j*3+1] += acc[j][1]; d[j*3+2] += acc[j][2];
        }
    }
    __syncthreads();

    // 4608 outputs, 512 threads -> 9 each; sum the 4 slices, one atomic each
    #pragma unroll
    for (int q = 0; q < 9; ++q) {
        int oid = t * 9 + q;
        int bb = oid / 72, c = oid - bb * 72;
        float s = Ls[0][bb][c] + Ls[1][bb][c] + Ls[2][bb][c] + Ls[3][bb][c];
        atomicAdd(&J[(size_t)bb * 72 + c], s);
    }
}

// per-(b,j): rodrigues -> R; lrotT [207][64]; level-parallel kinematic chain; G' [64][24][12]
__global__ __launch_bounds__(192)
void pose_kernel(const float* __restrict__ pose, const float* __restrict__ J,
                 float* __restrict__ G, float* __restrict__ lrotT)
{
    __shared__ float Gl[8][24][12];
    __shared__ float Gc[8][24][12];
    const int t  = threadIdx.x;
    const int bl = t / 24;
    const int j  = t % 24;
    const int b  = blockIdx.x * 8 + bl;

    float tx = pose[b*72 + j*3 + 0];
    float ty = pose[b*72 + j*3 + 1];
    float tz = pose[b*72 + j*3 + 2];
    float ax = tx + 1e-8f, ay = ty + 1e-8f, az = tz + 1e-8f;
    float angle = sqrtf(ax*ax + ay*ay + az*az);
    float nx = tx / angle, ny = ty / angle, nz = tz / angle;
    float half = 0.5f * angle;
    float sw = sinf(half);
    float qw = cosf(half), qx = sw*nx, qy = sw*ny, qz = sw*nz;
    float qn = sqrtf(qw*qw + qx*qx + qy*qy + qz*qz);
    qw /= qn; qx /= qn; qy /= qn; qz /= qn;
    float w2=qw*qw, x2=qx*qx, y2=qy*qy, z2=qz*qz;
    float xy=qx*qy, xz=qx*qz, yz=qy*qz, wx=qw*qx, wy=qw*qy, wz=qw*qz;
    float r00 = w2+x2-y2-z2, r01 = 2.f*(xy-wz), r02 = 2.f*(wy+xz);
    float r10 = 2.f*(wz+xy), r11 = w2-x2+y2-z2, r12 = 2.f*(yz-wx);
    float r20 = 2.f*(xz-wy), r21 = 2.f*(wx+yz), r22 = w2-x2-y2+z2;

    if (j >= 1) {   // lrotT[k][b], k = (j-1)*9 + c
        const int k9 = (j-1)*9;
        lrotT[(size_t)(k9+0)*64+b]=r00-1.f; lrotT[(size_t)(k9+1)*64+b]=r01;
        lrotT[(size_t)(k9+2)*64+b]=r02;     lrotT[(size_t)(k9+3)*64+b]=r10;
        lrotT[(size_t)(k9+4)*64+b]=r11-1.f; lrotT[(size_t)(k9+5)*64+b]=r12;
        lrotT[(size_t)(k9+6)*64+b]=r20;     lrotT[(size_t)(k9+7)*64+b]=r21;
        lrotT[(size_t)(k9+8)*64+b]=r22-1.f;
    }
    float jx = J[(size_t)(b*24+j)*3+0];
    float jy = J[(size_t)(b*24+j)*3+1];
    float jz = J[(size_t)(b*24+j)*3+2];
    float rx = jx, ry = jy, rz = jz;
    if (j > 0) {
        int p = c_par[j];
        rx -= J[(size_t)(b*24+p)*3+0];
        ry -= J[(size_t)(b*24+p)*3+1];
        rz -= J[(size_t)(b*24+p)*3+2];
    }
    float* gl = Gl[bl][j];
    gl[0]=r00; gl[1]=r01; gl[2]=r02;  gl[3]=rx;
    gl[4]=r10; gl[5]=r11; gl[6]=r12;  gl[7]=ry;
    gl[8]=r20; gl[9]=r21; gl[10]=r22; gl[11]=rz;
    __syncthreads();

    if (j == 0) {
        #pragma unroll
        for (int c = 0; c < 12; ++c) Gc[bl][0][c] = Gl[bl][0][c];
    }
    const int dj = c_depth[j];
    for (int lvl = 1; lvl <= 8; ++lvl) {
        __syncthreads();
        if (dj == lvl) {
            const float* Aa = Gc[bl][c_par[j]];
            const float* Bb = Gl[bl][j];
            float* D = Gc[bl][j];
            #pragma unroll
            for (int r = 0; r < 3; ++r) {
                float a0=Aa[r*4+0], a1=Aa[r*4+1], a2=Aa[r*4+2], a3=Aa[r*4+3];
                D[r*4+0] = a0*Bb[0] + a1*Bb[4] + a2*Bb[8];
                D[r*4+1] = a0*Bb[1] + a1*Bb[5] + a2*Bb[9];
                D[r*4+2] = a0*Bb[2] + a1*Bb[6] + a2*Bb[10];
                D[r*4+3] = a0*Bb[3] + a1*Bb[7] + a2*Bb[11] + a3;
            }
        }
    }
    __syncthreads();

    const float* Gi = Gc[bl][j];
    float* go = G + (size_t)(b*24 + j) * 12;
    #pragma unroll
    for (int r = 0; r < 3; ++r) {
        go[r*4+0] = Gi[r*4+0];
        go[r*4+1] = Gi[r*4+1];
        go[r*4+2] = Gi[r*4+2];
        go[r*4+3] = Gi[r*4+3] - (Gi[r*4+0]*jx + Gi[r*4+1]*jy + Gi[r*4+2]*jz);
    }
}

// out[b][v][d] = sum_j w[v][j] * (G'[b][j] applied to vp[b][v])
__global__ __launch_bounds__(256)
void skin_kernel(const float* __restrict__ vp, const float* __restrict__ G,
                 const float* __restrict__ wts, float* __restrict__ out)
{
    const int v = blockIdx.x * 256 + threadIdx.x;
    if (v >= NV) return;
    const int b0 = blockIdx.y * 8;
    float w[24];
    const float4* wp = (const float4*)(wts + (size_t)v * 24);
    #pragma unroll
    for (int q = 0; q < 6; ++q) {
        float4 t = wp[q];
        w[q*4+0]=t.x; w[q*4+1]=t.y; w[q*4+2]=t.z; w[q*4+3]=t.w;
    }
    for (int b = b0; b < b0 + 8; ++b) {
        const float* pb = vp + (size_t)b * NM + v*3;
        float px = pb[0], py = pb[1], pz = pb[2];
        float ox = 0.f, oy = 0.f, oz = 0.f;
        const float* Gb = G + (size_t)b * 24 * 12;
        #pragma unroll
        for (int j = 0; j < 24; ++j) {
            const float* g = Gb + j*12;   // uniform -> s_load
            float wj = w[j];
            ox += wj * (g[0]*px + g[1]*py + g[2]*pz  + g[3]);
            oy += wj * (g[4]*px + g[5]*py + g[6]*pz  + g[7]);
            oz += wj * (g[8]*px + g[9]*py + g[10]*pz + g[11]);
        }
        float* ob = out + (size_t)b * NM + v*3;
        ob[0] = ox; ob[1] = oy; ob[2] = oz;
    }
}

extern "C" void kernel_launch(void* const* d_in, const int* in_sizes, int n_in,
                              void* d_out, int out_size, void* d_ws, size_t ws_size,
                              hipStream_t stream) {
    const float* pose       = (const float*)d_in[0];
    const float* beta       = (const float*)d_in[1];
    const float* v_template = (const float*)d_in[2];
    const float* shapedirs  = (const float*)d_in[3];
    const float* posedirs   = (const float*)d_in[4];
    const float* Jreg       = (const float*)d_in[5];
    const float* weights    = (const float*)d_in[6];
    float* out = (float*)d_out;

    char* ws = (char*)d_ws;
    float* vs_ws    = (float*)(ws);                 // [NM][64]  38.4 MB
    float* vp_ws    = (float*)(ws + 38400000);      // [64][NM]  38.4 MB
    float* betaT_ws = (float*)(ws + 38400000);      // [300][64] aliases vp (dead before gemm2)
    float* J_ws     = (float*)(ws + 76800000);      // [64][24][3]
    float* G_ws     = (float*)(ws + 76818432);      // [64][24][12]
    float* lrotT_ws = (float*)(ws + 76892160);      // [207][64]

    prep_kernel<<<75, 256, 0, stream>>>(beta, betaT_ws, J_ws);
    gemm_mfma<300, 0><<<1172, 512, 0, stream>>>(shapedirs, betaT_ws, v_template, vs_ws);
    jreduce_kernel<<<250, 512, 0, stream>>>(vs_ws, Jreg, J_ws);
    pose_kernel<<<8, 192, 0, stream>>>(pose, J_ws, G_ws, lrotT_ws);
    gemm_mfma<207, 1><<<1172, 512, 0, stream>>>(posedirs, lrotT_ws, vs_ws, vp_ws);
    skin_kernel<<<dim3(196, 8), 256, 0, stream>>>(vp_ws, G_ws, weights, out);
}